// Round 12
// baseline (339.757 us; speedup 1.0000x reference)
//
#include <hip/hip_runtime.h>
#include <hip/hip_bf16.h>
#include <hip/hip_fp16.h>

#define IN_DIM 32
#define HID 64
#define H1 2
#define F1 (H1 * HID)   // 128
#define OUT_CH 64
#define NEG_SLOPE 0.2f
#define LN_EPS 1e-5f

#define BSHIFT 9                     // 512 nodes per bucket
#define BMASK ((1 << BSHIFT) - 1)
#define CHUNK 4096                   // edges per block in bucketing passes

typedef __attribute__((ext_vector_type(8))) short short8x;   // 8 bf16 = 4 VGPRs
typedef __attribute__((ext_vector_type(4))) float floatx4;   // MFMA accumulator

__device__ __forceinline__ float leaky(float x) {
    return x > 0.f ? x : NEG_SLOPE * x;
}
__device__ __forceinline__ float bf2f(__hip_bfloat16 v) { return __bfloat162float(v); }
__device__ __forceinline__ short f2bs(float v) {
    __hip_bfloat16 t = __float2bfloat16(v);
    return *reinterpret_cast<short*>(&t);
}
__device__ __forceinline__ float unpack_w(unsigned u, int hshift) {
    return __half2float(__ushort_as_half((unsigned short)(u >> hshift)));
}

// ---------------- bucketed CSR build ----------------

__global__ __launch_bounds__(256) void k_bhist(const int* __restrict__ dst, int E, int nb,
                                               int* __restrict__ bcnt) {
    __shared__ int h[512];
    int t = threadIdx.x;
    for (int i = t; i < nb; i += 256) h[i] = 0;
    __syncthreads();
    int base = blockIdx.x * CHUNK;
#pragma unroll
    for (int j = 0; j < 16; j++) {
        int e = base + j * 256 + t;
        if (e < E) atomicAdd(&h[dst[e] >> BSHIFT], 1);
    }
    __syncthreads();
    for (int i = t; i < nb; i += 256)
        if (h[i]) atomicAdd(&bcnt[i], h[i]);
}

__global__ __launch_bounds__(512) void k_bscan(const int* __restrict__ bcnt, int nb, int E,
                                               int* __restrict__ boff,
                                               int* __restrict__ bfill) {
    __shared__ int s[512];
    int t = threadIdx.x;
    int v = (t < nb) ? bcnt[t] : 0;
    s[t] = v;
    __syncthreads();
    for (int off = 1; off < 512; off <<= 1) {
        int u = (t >= off) ? s[t - off] : 0;
        __syncthreads();
        s[t] += u;
        __syncthreads();
    }
    if (t < nb) { int ex = s[t] - v; boff[t] = ex; bfill[t] = ex; }
    if (t == 0) boff[nb] = E;
}

__global__ __launch_bounds__(256) void k_bucket(const int* __restrict__ src,
                                                const int* __restrict__ dst, int E, int nb,
                                                int* __restrict__ bfill,
                                                unsigned int* __restrict__ bedge) {
    __shared__ int h[512];
    __shared__ int gb[512];
    int t = threadIdx.x;
    for (int i = t; i < nb; i += 256) h[i] = 0;
    __syncthreads();
    int base = blockIdx.x * CHUNK;
    unsigned int pk[16];
    int rk[16], bk[16];
#pragma unroll
    for (int j = 0; j < 16; j++) {
        int e = base + j * 256 + t;
        if (e < E) {
            int d = dst[e];
            int b = d >> BSHIFT;
            bk[j] = b;
            pk[j] = ((unsigned)src[e] << BSHIFT) | (unsigned)(d & BMASK);
            rk[j] = atomicAdd(&h[b], 1);
        } else bk[j] = -1;
    }
    __syncthreads();
    for (int i = t; i < nb; i += 256)
        gb[i] = h[i] ? atomicAdd(&bfill[i], h[i]) : 0;
    __syncthreads();
#pragma unroll
    for (int j = 0; j < 16; j++)
        if (bk[j] >= 0) bedge[gb[bk[j]] + rk[j]] = pk[j];
}

// one block per bucket: per-node counts + scan in LDS -> cnt/rowptr/col
__global__ __launch_bounds__(256) void k_csr(const unsigned int* __restrict__ bedge,
                                             const int* __restrict__ boff, int n,
                                             int* __restrict__ cnt,
                                             int* __restrict__ rowptr,
                                             int* __restrict__ col) {
    int b = blockIdx.x;
    int t = threadIdx.x;
    __shared__ int lcnt[512];
    __shared__ int lscan[256];
    int nbase = b << BSHIFT;
    lcnt[2 * t] = 0; lcnt[2 * t + 1] = 0;
    __syncthreads();
    int estart = boff[b], eend = boff[b + 1];
    for (int e = estart + t; e < eend; e += 256)
        atomicAdd(&lcnt[bedge[e] & BMASK], 1);
    __syncthreads();
    int c0 = lcnt[2 * t], c1 = lcnt[2 * t + 1];
    int s = c0 + c1;
    lscan[t] = s;
    __syncthreads();
    for (int off = 1; off < 256; off <<= 1) {
        int u = (t >= off) ? lscan[t - off] : 0;
        __syncthreads();
        lscan[t] += u;
        __syncthreads();
    }
    int ex = lscan[t] - s;
    int node0 = nbase + 2 * t, node1 = node0 + 1;
    if (node0 < n) { cnt[node0] = c0; rowptr[node0] = estart + ex; }
    if (node1 < n) { cnt[node1] = c1; rowptr[node1] = estart + ex + c0; }
    __syncthreads();
    lcnt[2 * t] = ex;
    lcnt[2 * t + 1] = ex + c0;
    __syncthreads();
    for (int e = estart + t; e < eend; e += 256) {
        unsigned int p = bedge[e];
        int pos = estart + atomicAdd(&lcnt[p & BMASK], 1);
        col[pos] = (int)(p >> BSHIFT);
    }
}

// ---------------- W pack + att-folded vectors ----------------
__global__ __launch_bounds__(256) void k_packW(const float* __restrict__ W1,
                                               const float* __restrict__ W2,
                                               const float* __restrict__ att_s,
                                               const float* __restrict__ att_d,
                                               __hip_bfloat16* __restrict__ W1t,
                                               __hip_bfloat16* __restrict__ W2t,
                                               float* __restrict__ wsd) {
    int idx = blockIdx.x * 256 + threadIdx.x;
    if (idx < IN_DIM * F1) {
        int ch = idx >> 5, k = idx & 31;
        W1t[idx] = __float2bfloat16(W1[k * F1 + ch]);
    }
    if (idx < F1 * OUT_CH) {
        int ch = idx >> 7, k = idx & 127;
        W2t[idx] = __float2bfloat16(W2[k * OUT_CH + ch]);
    }
    if (idx < 128) {
        int v = idx >> 5;              // 0: ws h0, 1: ws h1, 2: wd h0, 3: wd h1
        int k = idx & 31;
        const float* att = (v & 2) ? att_d : att_s;
        int h = v & 1;
        float s = 0.f;
#pragma unroll 8
        for (int c = 0; c < HID; c++)
            s = fmaf(W1[k * F1 + h * HID + c], att[h * HID + c], s);
        wsd[v * 32 + k] = s;
    }
}

// ---------------- per-node: xb16 cast + attention logits (as1/ad1 = x . wsd) ----------------
__global__ __launch_bounds__(256) void k_att1(const float* __restrict__ x,
                                              const float* __restrict__ wsd,
                                              __hip_bfloat16* __restrict__ xb16,
                                              float2* __restrict__ as1,
                                              float2* __restrict__ ad1, int n) {
    int node = blockIdx.x * 256 + threadIdx.x;
    if (node >= n) return;
    const float4* xp = (const float4*)(x + (size_t)node * IN_DIM);
    float4 xr[8];
#pragma unroll
    for (int i = 0; i < 8; i++) xr[i] = xp[i];
    const float* xf = (const float*)xr;
    short8x* xo = (short8x*)(xb16 + (size_t)node * IN_DIM);
#pragma unroll
    for (int i = 0; i < 4; i++) {
        short8x xb;
#pragma unroll
        for (int j = 0; j < 8; j++) xb[j] = f2bs(xf[i * 8 + j]);
        xo[i] = xb;
    }
    float d0 = 0.f, d1 = 0.f, d2 = 0.f, d3 = 0.f;
#pragma unroll
    for (int k = 0; k < 32; k++) {
        float xv = xf[k];
        d0 = fmaf(xv, wsd[k], d0);
        d1 = fmaf(xv, wsd[32 + k], d1);
        d2 = fmaf(xv, wsd[64 + k], d2);
        d3 = fmaf(xv, wsd[96 + k], d3);
    }
    as1[node] = make_float2(d0, d1);
    ad1[node] = make_float2(d2, d3);
}

// ---------------- Layer 1 aggregation in x-space: 64 B/edge gather, 16-deep MLP ----------------
__global__ __launch_bounds__(256) void k_agg1x(const __hip_bfloat16* __restrict__ xb16,
                                               const float2* __restrict__ as1p,
                                               const float2* __restrict__ ad1p,
                                               const int* __restrict__ rowptr,
                                               const int* __restrict__ cnt,
                                               const int* __restrict__ col,
                                               float* __restrict__ a, int n) {
    int node = blockIdx.x * 4 + (threadIdx.x >> 6);
    int lane = threadIdx.x & 63;
    if (node >= n) return;
    int c = lane & 31;
    int head = lane >> 5;
    int hshift = head << 4;
    float2 adn = ad1p[node];
    float2 asn = as1p[node];
    float w = __expf(leaky((head ? asn.y : asn.x) + (head ? adn.y : adn.x)));
    float acc = w * bf2f(xb16[(size_t)node * IN_DIM + c]);
    float wsum = w;
    int start = rowptr[node], deg = cnt[node];
    for (int base = 0; base < deg; base += 64) {
        int m = min(64, deg - base);
        int colv = 0; unsigned wvv = 0u;
        if (lane < m) {
            colv = col[start + base + lane];
            float2 as = as1p[colv];
            float w0 = __expf(leaky(as.x + adn.x));
            float w1 = __expf(leaky(as.y + adn.y));
            wvv = ((unsigned)__half_as_ushort(__float2half(w1)) << 16)
                | (unsigned)__half_as_ushort(__float2half(w0));
        }
        int j = 0;
        for (; j + 16 <= m; j += 16) {
            int sx[16]; unsigned ux[16];
#pragma unroll
            for (int q = 0; q < 16; q++) {
                sx[q] = __shfl(colv, j + q);
                ux[q] = __shfl(wvv, j + q);
            }
            __hip_bfloat16 gx[16];
#pragma unroll
            for (int q = 0; q < 16; q++) gx[q] = xb16[(size_t)sx[q] * IN_DIM + c];
#pragma unroll
            for (int q = 0; q < 16; q++) {
                float ww = unpack_w(ux[q], hshift);
                acc = fmaf(ww, bf2f(gx[q]), acc);
                wsum += ww;
            }
        }
        for (; j + 4 <= m; j += 4) {
            int sx[4]; unsigned ux[4];
#pragma unroll
            for (int q = 0; q < 4; q++) {
                sx[q] = __shfl(colv, j + q);
                ux[q] = __shfl(wvv, j + q);
            }
            __hip_bfloat16 gx[4];
#pragma unroll
            for (int q = 0; q < 4; q++) gx[q] = xb16[(size_t)sx[q] * IN_DIM + c];
#pragma unroll
            for (int q = 0; q < 4; q++) {
                float ww = unpack_w(ux[q], hshift);
                acc = fmaf(ww, bf2f(gx[q]), acc);
                wsum += ww;
            }
        }
        for (; j < m; j++) {
            int s = __shfl(colv, j);
            float ww = unpack_w(__shfl(wvv, j), hshift);
            acc = fmaf(ww, bf2f(xb16[(size_t)s * IN_DIM + c]), acc);
            wsum += ww;
        }
    }
    a[(size_t)node * 64 + lane] = acc / (wsum + 1e-16f);
}

// ---------------- a @ W1 + bias + LayerNorm + ReLU -> bf16 hln (MFMA) ----------------
__global__ __launch_bounds__(256) void k_ln1_mfma(const float* __restrict__ a,
                                                  const __hip_bfloat16* __restrict__ W1t,
                                                  const float* __restrict__ bias1,
                                                  const float* __restrict__ gamma,
                                                  const float* __restrict__ beta,
                                                  __hip_bfloat16* __restrict__ hlnb, int n) {
    int wave = threadIdx.x >> 6;
    int lane = threadIdx.x & 63;
    int row16 = lane & 15;
    int quad = lane >> 4;
    int node0 = blockIdx.x * 64 + wave * 16;

    short8x bfr[8];
#pragma unroll
    for (int nt = 0; nt < 8; nt++)
        bfr[nt] = *(const short8x*)(W1t + (nt * 16 + row16) * IN_DIM + quad * 8);

    int arow = node0 + row16;
    if (arow >= n) arow = n - 1;
    const float* ap = a + (size_t)arow * 64 + quad * 8;
    float4 p0 = *(const float4*)ap;
    float4 p1 = *(const float4*)(ap + 4);
    float4 p2 = *(const float4*)(ap + 32);
    float4 p3 = *(const float4*)(ap + 36);
    short8x af0, af1;
    af0[0] = f2bs(p0.x); af0[1] = f2bs(p0.y); af0[2] = f2bs(p0.z); af0[3] = f2bs(p0.w);
    af0[4] = f2bs(p1.x); af0[5] = f2bs(p1.y); af0[6] = f2bs(p1.z); af0[7] = f2bs(p1.w);
    af1[0] = f2bs(p2.x); af1[1] = f2bs(p2.y); af1[2] = f2bs(p2.z); af1[3] = f2bs(p2.w);
    af1[4] = f2bs(p3.x); af1[5] = f2bs(p3.y); af1[6] = f2bs(p3.z); af1[7] = f2bs(p3.w);

    floatx4 acc[8];
#pragma unroll
    for (int nt = 0; nt < 8; nt++) acc[nt] = (floatx4){0.f, 0.f, 0.f, 0.f};
#pragma unroll
    for (int nt = 0; nt < 8; nt++)
        acc[nt] = __builtin_amdgcn_mfma_f32_16x16x32_bf16(nt < 4 ? af0 : af1, bfr[nt],
                                                          acc[nt], 0, 0, 0);

    float bv[8], gv[8], btv[8];
#pragma unroll
    for (int nt = 0; nt < 8; nt++) {
        int ch = nt * 16 + row16;
        bv[nt] = bias1[ch];
        gv[nt] = gamma[ch];
        btv[nt] = beta[ch];
    }
#pragma unroll
    for (int rr = 0; rr < 4; rr++) {
        int node = node0 + quad * 4 + rr;
        float v[8];
        float sum = 0.f, sq = 0.f;
#pragma unroll
        for (int nt = 0; nt < 8; nt++) {
            v[nt] = acc[nt][rr] + bv[nt];
            sum += v[nt];
            sq += v[nt] * v[nt];
        }
#pragma unroll
        for (int off = 1; off < 16; off <<= 1) {
            sum += __shfl_xor(sum, off, 64);
            sq += __shfl_xor(sq, off, 64);
        }
        float mu = sum * (1.f / 128.f);
        float var = sq * (1.f / 128.f) - mu * mu;
        float r = rsqrtf(var + LN_EPS);
        if (node < n) {
#pragma unroll
            for (int nt = 0; nt < 8; nt++) {
                float o = (v[nt] - mu) * r * gv[nt] + btv[nt];
                hlnb[(size_t)node * F1 + nt * 16 + row16] = __float2bfloat16(fmaxf(o, 0.f));
            }
        }
    }
}

// ---------------- Layer 2 node transform via MFMA -> bf16 h2, att coefs ----------------
__global__ __launch_bounds__(256) void k_node2_mfma(const __hip_bfloat16* __restrict__ hlnb,
                                                    const __hip_bfloat16* __restrict__ W2t,
                                                    const float* __restrict__ att_s2,
                                                    const float* __restrict__ att_d2,
                                                    __hip_bfloat16* __restrict__ h2b,
                                                    float* __restrict__ as2,
                                                    float* __restrict__ ad2, int n) {
    int wave = threadIdx.x >> 6;
    int lane = threadIdx.x & 63;
    int row16 = lane & 15;
    int quad = lane >> 4;
    int node0 = blockIdx.x * 64 + wave * 16;

    short8x bfr[4][4];
#pragma unroll
    for (int nt = 0; nt < 4; nt++) {
        const __hip_bfloat16* wrow = W2t + (nt * 16 + row16) * F1 + quad * 8;
#pragma unroll
        for (int kc = 0; kc < 4; kc++)
            bfr[kc][nt] = *(const short8x*)(wrow + kc * 32);
    }

    floatx4 acc[4];
#pragma unroll
    for (int nt = 0; nt < 4; nt++) acc[nt] = (floatx4){0.f, 0.f, 0.f, 0.f};

    int arow = node0 + row16;
    if (arow >= n) arow = n - 1;
    const __hip_bfloat16* aptr = hlnb + (size_t)arow * F1 + quad * 8;
#pragma unroll
    for (int kc = 0; kc < 4; kc++) {
        short8x af = *(const short8x*)(aptr + kc * 32);
#pragma unroll
        for (int nt = 0; nt < 4; nt++)
            acc[nt] = __builtin_amdgcn_mfma_f32_16x16x32_bf16(af, bfr[kc][nt], acc[nt], 0, 0, 0);
    }

    float asv[4], adv[4];
#pragma unroll
    for (int nt = 0; nt < 4; nt++) {
        asv[nt] = att_s2[nt * 16 + row16];
        adv[nt] = att_d2[nt * 16 + row16];
    }
#pragma unroll
    for (int rr = 0; rr < 4; rr++) {
        int node = node0 + quad * 4 + rr;
        float ps = 0.f, pd = 0.f;
#pragma unroll
        for (int nt = 0; nt < 4; nt++) {
            float v = acc[nt][rr];
            if (node < n) h2b[(size_t)node * OUT_CH + nt * 16 + row16] = __float2bfloat16(v);
            ps = fmaf(v, asv[nt], ps);
            pd = fmaf(v, adv[nt], pd);
        }
#pragma unroll
        for (int off = 1; off < 16; off <<= 1) {
            ps += __shfl_xor(ps, off, 64);
            pd += __shfl_xor(pd, off, 64);
        }
        if (row16 == 0 && node < n) { as2[node] = ps; ad2[node] = pd; }
    }
}

// ---------------- Layer 2 aggregation + bias -> output, 16-deep MLP ----------------
__global__ __launch_bounds__(256) void k_agg2(const __hip_bfloat16* __restrict__ h2b,
                                              const float* __restrict__ as2,
                                              const float* __restrict__ ad2,
                                              const int* __restrict__ rowptr,
                                              const int* __restrict__ cnt,
                                              const int* __restrict__ col,
                                              const float* __restrict__ bias2,
                                              float* __restrict__ out, int n) {
    int node = blockIdx.x * 4 + (threadIdx.x >> 6);
    int lane = threadIdx.x & 63;
    if (node >= n) return;
    float adn = ad2[node];
    float w = __expf(leaky(as2[node] + adn));     // self loop
    float acc = w * bf2f(h2b[(size_t)node * OUT_CH + lane]);
    float wsum = w;
    int start = rowptr[node], deg = cnt[node];
    for (int base = 0; base < deg; base += 64) {
        int m = min(64, deg - base);
        int colv = 0; float wvv = 0.f;
        if (lane < m) {
            colv = col[start + base + lane];
            wvv = __expf(leaky(as2[colv] + adn));
        }
        int j = 0;
        for (; j + 16 <= m; j += 16) {
            int sx[16]; float wx[16];
#pragma unroll
            for (int q = 0; q < 16; q++) {
                sx[q] = __shfl(colv, j + q);
                wx[q] = __shfl(wvv, j + q);
            }
            __hip_bfloat16 gx[16];
#pragma unroll
            for (int q = 0; q < 16; q++) gx[q] = h2b[(size_t)sx[q] * OUT_CH + lane];
#pragma unroll
            for (int q = 0; q < 16; q++) {
                acc = fmaf(wx[q], bf2f(gx[q]), acc);
                wsum += wx[q];
            }
        }
        for (; j + 4 <= m; j += 4) {
            int sx[4]; float wx[4];
#pragma unroll
            for (int q = 0; q < 4; q++) {
                sx[q] = __shfl(colv, j + q);
                wx[q] = __shfl(wvv, j + q);
            }
            __hip_bfloat16 gx[4];
#pragma unroll
            for (int q = 0; q < 4; q++) gx[q] = h2b[(size_t)sx[q] * OUT_CH + lane];
#pragma unroll
            for (int q = 0; q < 4; q++) {
                acc = fmaf(wx[q], bf2f(gx[q]), acc);
                wsum += wx[q];
            }
        }
        for (; j < m; j++) {
            int s = __shfl(colv, j);
            float ww = __shfl(wvv, j);
            acc = fmaf(ww, bf2f(h2b[(size_t)s * OUT_CH + lane]), acc);
            wsum += ww;
        }
    }
    out[(size_t)node * OUT_CH + lane] = acc / (wsum + 1e-16f) + bias2[lane];
}

extern "C" void kernel_launch(void* const* d_in, const int* in_sizes, int n_in,
                              void* d_out, int out_size, void* d_ws, size_t ws_size,
                              hipStream_t stream) {
    const float* x        = (const float*)d_in[0];
    const int*   eidx     = (const int*)d_in[1];
    const float* W1       = (const float*)d_in[2];
    const float* att_src1 = (const float*)d_in[3];
    const float* att_dst1 = (const float*)d_in[4];
    const float* bias1    = (const float*)d_in[5];
    const float* gamma    = (const float*)d_in[6];
    const float* beta     = (const float*)d_in[7];
    const float* W2       = (const float*)d_in[8];
    const float* att_src2 = (const float*)d_in[9];
    const float* att_dst2 = (const float*)d_in[10];
    const float* bias2    = (const float*)d_in[11];
    float* out = (float*)d_out;

    const int N = in_sizes[0] / IN_DIM;      // 100000
    const int E = in_sizes[1] / 2;           // 1600000
    const int* src = eidx;
    const int* dst = eidx + E;
    const int nb = (N + BMASK) >> BSHIFT;    // 196 buckets

    char* w = (char*)d_ws;
    __hip_bfloat16* xb16  = (__hip_bfloat16*)w;  w += (size_t)N * IN_DIM * 2;   // 6.4 MB
    float* a              = (float*)w;           w += (size_t)N * 64 * 4;       // 25.6 MB
    __hip_bfloat16* hlnb  = (__hip_bfloat16*)w;  w += (size_t)N * F1 * 2;       // 25.6 MB
    __hip_bfloat16* h2b   = (__hip_bfloat16*)w;  w += (size_t)N * OUT_CH * 2;   // 12.8 MB
    __hip_bfloat16* W1t   = (__hip_bfloat16*)w;  w += IN_DIM * F1 * 2;
    __hip_bfloat16* W2t   = (__hip_bfloat16*)w;  w += F1 * OUT_CH * 2;
    float* wsd = (float*)w; w += 128 * 4;
    float* as1 = (float*)w; w += (size_t)N * 2 * 4;
    float* ad1 = (float*)w; w += (size_t)N * 2 * 4;
    float* as2 = (float*)w; w += (size_t)N * 4;
    float* ad2 = (float*)w; w += (size_t)N * 4;
    int* cnt    = (int*)w; w += (size_t)N * 4;
    int* rowptr = (int*)w; w += (size_t)N * 4;
    int* bcnt   = (int*)w; w += 512 * 4;
    int* boff   = (int*)w; w += 520 * 4;
    int* bfill  = (int*)w; w += 512 * 4;
    int* col    = (int*)w; w += (size_t)E * 4;
    unsigned int* bedge = (unsigned int*)w; w += (size_t)E * 4;

    const int nchunk = (E + CHUNK - 1) / CHUNK;   // 391

    // ---- bucketed CSR build (shared by both layers) ----
    hipMemsetAsync(bcnt, 0, 512 * 4, stream);
    k_bhist<<<nchunk, 256, 0, stream>>>(dst, E, nb, bcnt);
    k_bscan<<<1, 512, 0, stream>>>(bcnt, nb, E, boff, bfill);
    k_bucket<<<nchunk, 256, 0, stream>>>(src, dst, E, nb, bfill, bedge);
    k_csr<<<nb, 256, 0, stream>>>(bedge, boff, N, cnt, rowptr, col);

    // ---- Layer 1 (x-space aggregation) ----
    k_packW<<<(F1 * OUT_CH + 255) / 256, 256, 0, stream>>>(W1, W2, att_src1, att_dst1,
                                                           W1t, W2t, wsd);
    k_att1<<<(N + 255) / 256, 256, 0, stream>>>(x, wsd, xb16,
                                                (float2*)as1, (float2*)ad1, N);
    k_agg1x<<<(N + 3) / 4, 256, 0, stream>>>(xb16, (const float2*)as1, (const float2*)ad1,
                                             rowptr, cnt, col, a, N);
    k_ln1_mfma<<<(N + 63) / 64, 256, 0, stream>>>(a, W1t, bias1, gamma, beta, hlnb, N);

    // ---- Layer 2 ----
    k_node2_mfma<<<(N + 63) / 64, 256, 0, stream>>>(hlnb, W2t, att_src2, att_dst2,
                                                    h2b, as2, ad2, N);
    k_agg2<<<(N + 3) / 4, 256, 0, stream>>>(h2b, as2, ad2, rowptr, cnt, col,
                                            bias2, out, N);
}

// Round 13
// 306.587 us; speedup vs baseline: 1.1082x; 1.1082x over previous
//
#include <hip/hip_runtime.h>
#include <hip/hip_bf16.h>
#include <hip/hip_fp16.h>

#define IN_DIM 32
#define HID 64
#define H1 2
#define F1 (H1 * HID)   // 128
#define OUT_CH 64
#define NEG_SLOPE 0.2f
#define LN_EPS 1e-5f

#define BSHIFT 9                     // 512 nodes per bucket
#define BMASK ((1 << BSHIFT) - 1)
#define CHUNK 4096                   // edges per block in bucketing passes

typedef __attribute__((ext_vector_type(8))) short short8x;   // 8 bf16 = 4 VGPRs
typedef __attribute__((ext_vector_type(4))) float floatx4;   // MFMA accumulator

__device__ __forceinline__ float leaky(float x) {
    return x > 0.f ? x : NEG_SLOPE * x;
}
__device__ __forceinline__ float bf2f(__hip_bfloat16 v) { return __bfloat162float(v); }
__device__ __forceinline__ short f2bs(float v) {
    __hip_bfloat16 t = __float2bfloat16(v);
    return *reinterpret_cast<short*>(&t);
}
__device__ __forceinline__ float unpack_w(unsigned u, int hshift) {
    return __half2float(__ushort_as_half((unsigned short)(u >> hshift)));
}

// ---------------- bucketed CSR build ----------------

__global__ __launch_bounds__(256) void k_bhist(const int* __restrict__ dst, int E, int nb,
                                               int* __restrict__ bcnt) {
    __shared__ int h[512];
    int t = threadIdx.x;
    for (int i = t; i < nb; i += 256) h[i] = 0;
    __syncthreads();
    int base = blockIdx.x * CHUNK;
#pragma unroll
    for (int j = 0; j < 16; j++) {
        int e = base + j * 256 + t;
        if (e < E) atomicAdd(&h[dst[e] >> BSHIFT], 1);
    }
    __syncthreads();
    for (int i = t; i < nb; i += 256)
        if (h[i]) atomicAdd(&bcnt[i], h[i]);
}

__global__ __launch_bounds__(512) void k_bscan(const int* __restrict__ bcnt, int nb, int E,
                                               int* __restrict__ boff,
                                               int* __restrict__ bfill) {
    __shared__ int s[512];
    int t = threadIdx.x;
    int v = (t < nb) ? bcnt[t] : 0;
    s[t] = v;
    __syncthreads();
    for (int off = 1; off < 512; off <<= 1) {
        int u = (t >= off) ? s[t - off] : 0;
        __syncthreads();
        s[t] += u;
        __syncthreads();
    }
    if (t < nb) { int ex = s[t] - v; boff[t] = ex; bfill[t] = ex; }
    if (t == 0) boff[nb] = E;
}

__global__ __launch_bounds__(256) void k_bucket(const int* __restrict__ src,
                                                const int* __restrict__ dst, int E, int nb,
                                                int* __restrict__ bfill,
                                                unsigned int* __restrict__ bedge) {
    __shared__ int h[512];
    __shared__ int gb[512];
    int t = threadIdx.x;
    for (int i = t; i < nb; i += 256) h[i] = 0;
    __syncthreads();
    int base = blockIdx.x * CHUNK;
    unsigned int pk[16];
    int rk[16], bk[16];
#pragma unroll
    for (int j = 0; j < 16; j++) {
        int e = base + j * 256 + t;
        if (e < E) {
            int d = dst[e];
            int b = d >> BSHIFT;
            bk[j] = b;
            pk[j] = ((unsigned)src[e] << BSHIFT) | (unsigned)(d & BMASK);
            rk[j] = atomicAdd(&h[b], 1);
        } else bk[j] = -1;
    }
    __syncthreads();
    for (int i = t; i < nb; i += 256)
        gb[i] = h[i] ? atomicAdd(&bfill[i], h[i]) : 0;
    __syncthreads();
#pragma unroll
    for (int j = 0; j < 16; j++)
        if (bk[j] >= 0) bedge[gb[bk[j]] + rk[j]] = pk[j];
}

// one block per bucket: per-node counts + scan in LDS -> cnt/rowptr/col
__global__ __launch_bounds__(256) void k_csr(const unsigned int* __restrict__ bedge,
                                             const int* __restrict__ boff, int n,
                                             int* __restrict__ cnt,
                                             int* __restrict__ rowptr,
                                             int* __restrict__ col) {
    int b = blockIdx.x;
    int t = threadIdx.x;
    __shared__ int lcnt[512];
    __shared__ int lscan[256];
    int nbase = b << BSHIFT;
    lcnt[2 * t] = 0; lcnt[2 * t + 1] = 0;
    __syncthreads();
    int estart = boff[b], eend = boff[b + 1];
    for (int e = estart + t; e < eend; e += 256)
        atomicAdd(&lcnt[bedge[e] & BMASK], 1);
    __syncthreads();
    int c0 = lcnt[2 * t], c1 = lcnt[2 * t + 1];
    int s = c0 + c1;
    lscan[t] = s;
    __syncthreads();
    for (int off = 1; off < 256; off <<= 1) {
        int u = (t >= off) ? lscan[t - off] : 0;
        __syncthreads();
        lscan[t] += u;
        __syncthreads();
    }
    int ex = lscan[t] - s;
    int node0 = nbase + 2 * t, node1 = node0 + 1;
    if (node0 < n) { cnt[node0] = c0; rowptr[node0] = estart + ex; }
    if (node1 < n) { cnt[node1] = c1; rowptr[node1] = estart + ex + c0; }
    __syncthreads();
    lcnt[2 * t] = ex;
    lcnt[2 * t + 1] = ex + c0;
    __syncthreads();
    for (int e = estart + t; e < eend; e += 256) {
        unsigned int p = bedge[e];
        int pos = estart + atomicAdd(&lcnt[p & BMASK], 1);
        col[pos] = (int)(p >> BSHIFT);
    }
}

// ---------------- W pack + att-folded vectors ----------------
__global__ __launch_bounds__(256) void k_packW(const float* __restrict__ W1,
                                               const float* __restrict__ W2,
                                               const float* __restrict__ att_s,
                                               const float* __restrict__ att_d,
                                               __hip_bfloat16* __restrict__ W1t,
                                               __hip_bfloat16* __restrict__ W2t,
                                               float* __restrict__ wsd) {
    int idx = blockIdx.x * 256 + threadIdx.x;
    if (idx < IN_DIM * F1) {
        int ch = idx >> 5, k = idx & 31;
        W1t[idx] = __float2bfloat16(W1[k * F1 + ch]);
    }
    if (idx < F1 * OUT_CH) {
        int ch = idx >> 7, k = idx & 127;
        W2t[idx] = __float2bfloat16(W2[k * OUT_CH + ch]);
    }
    if (idx < 128) {
        int v = idx >> 5;              // 0: ws h0, 1: ws h1, 2: wd h0, 3: wd h1
        int k = idx & 31;
        const float* att = (v & 2) ? att_d : att_s;
        int h = v & 1;
        float s = 0.f;
#pragma unroll 8
        for (int c = 0; c < HID; c++)
            s = fmaf(W1[k * F1 + h * HID + c], att[h * HID + c], s);
        wsd[v * 32 + k] = s;
    }
}

// ---------------- per-node: xb16 cast + attention logits (as1/ad1 = x . wsd) ----------------
__global__ __launch_bounds__(256) void k_att1(const float* __restrict__ x,
                                              const float* __restrict__ wsd,
                                              __hip_bfloat16* __restrict__ xb16,
                                              float2* __restrict__ as1,
                                              float2* __restrict__ ad1, int n) {
    int node = blockIdx.x * 256 + threadIdx.x;
    if (node >= n) return;
    const float4* xp = (const float4*)(x + (size_t)node * IN_DIM);
    float4 xr[8];
#pragma unroll
    for (int i = 0; i < 8; i++) xr[i] = xp[i];
    const float* xf = (const float*)xr;
    short8x* xo = (short8x*)(xb16 + (size_t)node * IN_DIM);
#pragma unroll
    for (int i = 0; i < 4; i++) {
        short8x xb;
#pragma unroll
        for (int j = 0; j < 8; j++) xb[j] = f2bs(xf[i * 8 + j]);
        xo[i] = xb;
    }
    float d0 = 0.f, d1 = 0.f, d2 = 0.f, d3 = 0.f;
#pragma unroll
    for (int k = 0; k < 32; k++) {
        float xv = xf[k];
        d0 = fmaf(xv, wsd[k], d0);
        d1 = fmaf(xv, wsd[32 + k], d1);
        d2 = fmaf(xv, wsd[64 + k], d2);
        d3 = fmaf(xv, wsd[96 + k], d3);
    }
    as1[node] = make_float2(d0, d1);
    ad1[node] = make_float2(d2, d3);
}

// ---------------- Layer 1 aggregation in x-space: 64 B/edge gather (8-deep) -> bf16 a ----------------
__global__ __launch_bounds__(256) void k_agg1x(const __hip_bfloat16* __restrict__ xb16,
                                               const float2* __restrict__ as1p,
                                               const float2* __restrict__ ad1p,
                                               const int* __restrict__ rowptr,
                                               const int* __restrict__ cnt,
                                               const int* __restrict__ col,
                                               __hip_bfloat16* __restrict__ a, int n) {
    int node = blockIdx.x * 4 + (threadIdx.x >> 6);
    int lane = threadIdx.x & 63;
    if (node >= n) return;
    int c = lane & 31;
    int head = lane >> 5;
    int hshift = head << 4;
    float2 adn = ad1p[node];
    float2 asn = as1p[node];
    float w = __expf(leaky((head ? asn.y : asn.x) + (head ? adn.y : adn.x)));
    float acc = w * bf2f(xb16[(size_t)node * IN_DIM + c]);
    float wsum = w;
    int start = rowptr[node], deg = cnt[node];
    for (int base = 0; base < deg; base += 64) {
        int m = min(64, deg - base);
        int colv = 0; unsigned wvv = 0u;
        if (lane < m) {
            colv = col[start + base + lane];
            float2 as = as1p[colv];
            float w0 = __expf(leaky(as.x + adn.x));
            float w1 = __expf(leaky(as.y + adn.y));
            wvv = ((unsigned)__half_as_ushort(__float2half(w1)) << 16)
                | (unsigned)__half_as_ushort(__float2half(w0));
        }
        int j = 0;
        for (; j + 8 <= m; j += 8) {
            int sx[8]; unsigned ux[8];
#pragma unroll
            for (int q = 0; q < 8; q++) {
                sx[q] = __shfl(colv, j + q);
                ux[q] = __shfl(wvv, j + q);
            }
            __hip_bfloat16 gx[8];
#pragma unroll
            for (int q = 0; q < 8; q++) gx[q] = xb16[(size_t)sx[q] * IN_DIM + c];
#pragma unroll
            for (int q = 0; q < 8; q++) {
                float ww = unpack_w(ux[q], hshift);
                acc = fmaf(ww, bf2f(gx[q]), acc);
                wsum += ww;
            }
        }
        for (; j < m; j++) {
            int s = __shfl(colv, j);
            float ww = unpack_w(__shfl(wvv, j), hshift);
            acc = fmaf(ww, bf2f(xb16[(size_t)s * IN_DIM + c]), acc);
            wsum += ww;
        }
    }
    a[(size_t)node * 64 + lane] = __float2bfloat16(acc / (wsum + 1e-16f));
}

// ---------------- a(bf16) @ W1 + bias + LayerNorm + ReLU -> bf16 hln (MFMA) ----------------
__global__ __launch_bounds__(256) void k_ln1_mfma(const __hip_bfloat16* __restrict__ a,
                                                  const __hip_bfloat16* __restrict__ W1t,
                                                  const float* __restrict__ bias1,
                                                  const float* __restrict__ gamma,
                                                  const float* __restrict__ beta,
                                                  __hip_bfloat16* __restrict__ hlnb, int n) {
    int wave = threadIdx.x >> 6;
    int lane = threadIdx.x & 63;
    int row16 = lane & 15;
    int quad = lane >> 4;
    int node0 = blockIdx.x * 64 + wave * 16;

    short8x bfr[8];
#pragma unroll
    for (int nt = 0; nt < 8; nt++)
        bfr[nt] = *(const short8x*)(W1t + (nt * 16 + row16) * IN_DIM + quad * 8);

    int arow = node0 + row16;
    if (arow >= n) arow = n - 1;
    const __hip_bfloat16* ap = a + (size_t)arow * 64 + quad * 8;
    short8x af0 = *(const short8x*)ap;          // head0 channels (k 0..31)
    short8x af1 = *(const short8x*)(ap + 32);   // head1 channels (k 32..63)

    floatx4 acc[8];
#pragma unroll
    for (int nt = 0; nt < 8; nt++) acc[nt] = (floatx4){0.f, 0.f, 0.f, 0.f};
#pragma unroll
    for (int nt = 0; nt < 8; nt++)
        acc[nt] = __builtin_amdgcn_mfma_f32_16x16x32_bf16(nt < 4 ? af0 : af1, bfr[nt],
                                                          acc[nt], 0, 0, 0);

    float bv[8], gv[8], btv[8];
#pragma unroll
    for (int nt = 0; nt < 8; nt++) {
        int ch = nt * 16 + row16;
        bv[nt] = bias1[ch];
        gv[nt] = gamma[ch];
        btv[nt] = beta[ch];
    }
#pragma unroll
    for (int rr = 0; rr < 4; rr++) {
        int node = node0 + quad * 4 + rr;
        float v[8];
        float sum = 0.f, sq = 0.f;
#pragma unroll
        for (int nt = 0; nt < 8; nt++) {
            v[nt] = acc[nt][rr] + bv[nt];
            sum += v[nt];
            sq += v[nt] * v[nt];
        }
#pragma unroll
        for (int off = 1; off < 16; off <<= 1) {
            sum += __shfl_xor(sum, off, 64);
            sq += __shfl_xor(sq, off, 64);
        }
        float mu = sum * (1.f / 128.f);
        float var = sq * (1.f / 128.f) - mu * mu;
        float r = rsqrtf(var + LN_EPS);
        if (node < n) {
#pragma unroll
            for (int nt = 0; nt < 8; nt++) {
                float o = (v[nt] - mu) * r * gv[nt] + btv[nt];
                hlnb[(size_t)node * F1 + nt * 16 + row16] = __float2bfloat16(fmaxf(o, 0.f));
            }
        }
    }
}

// ---------------- Layer 2 node transform via MFMA -> bf16 h2, att coefs ----------------
__global__ __launch_bounds__(256) void k_node2_mfma(const __hip_bfloat16* __restrict__ hlnb,
                                                    const __hip_bfloat16* __restrict__ W2t,
                                                    const float* __restrict__ att_s2,
                                                    const float* __restrict__ att_d2,
                                                    __hip_bfloat16* __restrict__ h2b,
                                                    float* __restrict__ as2,
                                                    float* __restrict__ ad2, int n) {
    int wave = threadIdx.x >> 6;
    int lane = threadIdx.x & 63;
    int row16 = lane & 15;
    int quad = lane >> 4;
    int node0 = blockIdx.x * 64 + wave * 16;

    short8x bfr[4][4];
#pragma unroll
    for (int nt = 0; nt < 4; nt++) {
        const __hip_bfloat16* wrow = W2t + (nt * 16 + row16) * F1 + quad * 8;
#pragma unroll
        for (int kc = 0; kc < 4; kc++)
            bfr[kc][nt] = *(const short8x*)(wrow + kc * 32);
    }

    floatx4 acc[4];
#pragma unroll
    for (int nt = 0; nt < 4; nt++) acc[nt] = (floatx4){0.f, 0.f, 0.f, 0.f};

    int arow = node0 + row16;
    if (arow >= n) arow = n - 1;
    const __hip_bfloat16* aptr = hlnb + (size_t)arow * F1 + quad * 8;
#pragma unroll
    for (int kc = 0; kc < 4; kc++) {
        short8x af = *(const short8x*)(aptr + kc * 32);
#pragma unroll
        for (int nt = 0; nt < 4; nt++)
            acc[nt] = __builtin_amdgcn_mfma_f32_16x16x32_bf16(af, bfr[kc][nt], acc[nt], 0, 0, 0);
    }

    float asv[4], adv[4];
#pragma unroll
    for (int nt = 0; nt < 4; nt++) {
        asv[nt] = att_s2[nt * 16 + row16];
        adv[nt] = att_d2[nt * 16 + row16];
    }
#pragma unroll
    for (int rr = 0; rr < 4; rr++) {
        int node = node0 + quad * 4 + rr;
        float ps = 0.f, pd = 0.f;
#pragma unroll
        for (int nt = 0; nt < 4; nt++) {
            float v = acc[nt][rr];
            if (node < n) h2b[(size_t)node * OUT_CH + nt * 16 + row16] = __float2bfloat16(v);
            ps = fmaf(v, asv[nt], ps);
            pd = fmaf(v, adv[nt], pd);
        }
#pragma unroll
        for (int off = 1; off < 16; off <<= 1) {
            ps += __shfl_xor(ps, off, 64);
            pd += __shfl_xor(pd, off, 64);
        }
        if (row16 == 0 && node < n) { as2[node] = ps; ad2[node] = pd; }
    }
}

// ---------------- Layer 2 aggregation: edge-pair scheme ----------------
// lane hl=lane&31 covers channels {2hl,2hl+1} (bf16x2); half=lane>>5 takes edge 2p+half.
// Per edge-pair: 1 gather instr (2 rows), 2 shfl, 2 fma/lane. Halves combined by shfl_xor(32).
__global__ __launch_bounds__(256) void k_agg2(const __hip_bfloat162* __restrict__ h2b2,
                                              const float* __restrict__ as2,
                                              const float* __restrict__ ad2,
                                              const int* __restrict__ rowptr,
                                              const int* __restrict__ cnt,
                                              const int* __restrict__ col,
                                              const float* __restrict__ bias2,
                                              float* __restrict__ out, int n) {
    int node = blockIdx.x * 4 + (threadIdx.x >> 6);
    int lane = threadIdx.x & 63;
    if (node >= n) return;
    int hl = lane & 31;
    int half = lane >> 5;
    float adn = ad2[node];
    float w = __expf(leaky(as2[node] + adn));     // self loop (seed on half 0 only)
    __hip_bfloat162 hv = h2b2[(size_t)node * 32 + hl];
    float acc0 = half ? 0.f : w * bf2f(hv.x);
    float acc1 = half ? 0.f : w * bf2f(hv.y);
    float wsum = half ? 0.f : w;
    int start = rowptr[node], deg = cnt[node];
    for (int base = 0; base < deg; base += 64) {
        int m = min(64, deg - base);
        int colv = 0; float wvv = 0.f;               // wvv=0 for invalid lanes => safe padding
        if (lane < m) {
            colv = col[start + base + lane];
            wvv = __expf(leaky(as2[colv] + adn));
        }
        int P = (m + 1) >> 1;                        // edge pairs in this chunk
        int p = 0;
        for (; p + 8 <= P; p += 8) {
            int sx[8]; float wx[8];
#pragma unroll
            for (int q = 0; q < 8; q++) {
                int k = 2 * (p + q) + half;          // k<=63 always; wvv=0 beyond m
                sx[q] = __shfl(colv, k);
                wx[q] = __shfl(wvv, k);
            }
            __hip_bfloat162 gx[8];
#pragma unroll
            for (int q = 0; q < 8; q++) gx[q] = h2b2[(size_t)sx[q] * 32 + hl];
#pragma unroll
            for (int q = 0; q < 8; q++) {
                acc0 = fmaf(wx[q], bf2f(gx[q].x), acc0);
                acc1 = fmaf(wx[q], bf2f(gx[q].y), acc1);
                wsum += wx[q];
            }
        }
        for (; p < P; p++) {
            int k = 2 * p + half;
            int s = __shfl(colv, k);
            float wk = __shfl(wvv, k);
            __hip_bfloat162 g = h2b2[(size_t)s * 32 + hl];
            acc0 = fmaf(wk, bf2f(g.x), acc0);
            acc1 = fmaf(wk, bf2f(g.y), acc1);
            wsum += wk;
        }
    }
    acc0 += __shfl_xor(acc0, 32, 64);
    acc1 += __shfl_xor(acc1, 32, 64);
    wsum += __shfl_xor(wsum, 32, 64);
    float inv = 1.f / (wsum + 1e-16f);
    if (half == 0) {
        float2 bv = ((const float2*)bias2)[hl];
        float2 ov;
        ov.x = acc0 * inv + bv.x;
        ov.y = acc1 * inv + bv.y;
        ((float2*)out)[(size_t)node * 32 + hl] = ov;
    }
}

extern "C" void kernel_launch(void* const* d_in, const int* in_sizes, int n_in,
                              void* d_out, int out_size, void* d_ws, size_t ws_size,
                              hipStream_t stream) {
    const float* x        = (const float*)d_in[0];
    const int*   eidx     = (const int*)d_in[1];
    const float* W1       = (const float*)d_in[2];
    const float* att_src1 = (const float*)d_in[3];
    const float* att_dst1 = (const float*)d_in[4];
    const float* bias1    = (const float*)d_in[5];
    const float* gamma    = (const float*)d_in[6];
    const float* beta     = (const float*)d_in[7];
    const float* W2       = (const float*)d_in[8];
    const float* att_src2 = (const float*)d_in[9];
    const float* att_dst2 = (const float*)d_in[10];
    const float* bias2    = (const float*)d_in[11];
    float* out = (float*)d_out;

    const int N = in_sizes[0] / IN_DIM;      // 100000
    const int E = in_sizes[1] / 2;           // 1600000
    const int* src = eidx;
    const int* dst = eidx + E;
    const int nb = (N + BMASK) >> BSHIFT;    // 196 buckets

    char* w = (char*)d_ws;
    __hip_bfloat16* xb16  = (__hip_bfloat16*)w;  w += (size_t)N * IN_DIM * 2;   // 6.4 MB
    __hip_bfloat16* a     = (__hip_bfloat16*)w;  w += (size_t)N * 64 * 2;       // 12.8 MB
    __hip_bfloat16* hlnb  = (__hip_bfloat16*)w;  w += (size_t)N * F1 * 2;       // 25.6 MB
    __hip_bfloat16* h2b   = (__hip_bfloat16*)w;  w += (size_t)N * OUT_CH * 2;   // 12.8 MB
    __hip_bfloat16* W1t   = (__hip_bfloat16*)w;  w += IN_DIM * F1 * 2;
    __hip_bfloat16* W2t   = (__hip_bfloat16*)w;  w += F1 * OUT_CH * 2;
    float* wsd = (float*)w; w += 128 * 4;
    float* as1 = (float*)w; w += (size_t)N * 2 * 4;
    float* ad1 = (float*)w; w += (size_t)N * 2 * 4;
    float* as2 = (float*)w; w += (size_t)N * 4;
    float* ad2 = (float*)w; w += (size_t)N * 4;
    int* cnt    = (int*)w; w += (size_t)N * 4;
    int* rowptr = (int*)w; w += (size_t)N * 4;
    int* bcnt   = (int*)w; w += 512 * 4;
    int* boff   = (int*)w; w += 520 * 4;
    int* bfill  = (int*)w; w += 512 * 4;
    int* col    = (int*)w; w += (size_t)E * 4;
    unsigned int* bedge = (unsigned int*)w; w += (size_t)E * 4;

    const int nchunk = (E + CHUNK - 1) / CHUNK;   // 391

    // ---- bucketed CSR build (shared by both layers) ----
    hipMemsetAsync(bcnt, 0, 512 * 4, stream);
    k_bhist<<<nchunk, 256, 0, stream>>>(dst, E, nb, bcnt);
    k_bscan<<<1, 512, 0, stream>>>(bcnt, nb, E, boff, bfill);
    k_bucket<<<nchunk, 256, 0, stream>>>(src, dst, E, nb, bfill, bedge);
    k_csr<<<nb, 256, 0, stream>>>(bedge, boff, N, cnt, rowptr, col);

    // ---- Layer 1 (x-space aggregation) ----
    k_packW<<<(F1 * OUT_CH + 255) / 256, 256, 0, stream>>>(W1, W2, att_src1, att_dst1,
                                                           W1t, W2t, wsd);
    k_att1<<<(N + 255) / 256, 256, 0, stream>>>(x, wsd, xb16,
                                                (float2*)as1, (float2*)ad1, N);
    k_agg1x<<<(N + 3) / 4, 256, 0, stream>>>(xb16, (const float2*)as1, (const float2*)ad1,
                                             rowptr, cnt, col, a, N);
    k_ln1_mfma<<<(N + 63) / 64, 256, 0, stream>>>(a, W1t, bias1, gamma, beta, hlnb, N);

    // ---- Layer 2 ----
    k_node2_mfma<<<(N + 63) / 64, 256, 0, stream>>>(hlnb, W2t, att_src2, att_dst2,
                                                    h2b, as2, ad2, N);
    k_agg2<<<(N + 3) / 4, 256, 0, stream>>>((const __hip_bfloat162*)h2b, as2, ad2,
                                            rowptr, cnt, col, bias2, out, N);
}